// Round 4
// baseline (64.953 us; speedup 1.0000x reference)
//
#include <hip/hip_runtime.h>

#define D 1024
#define EPS 1e-6f

// Native clang vector type: accepted by __builtin_nontemporal_{load,store}.
typedef float f4 __attribute__((ext_vector_type(4)));

// One WAVE (64 lanes) per TWO token rows; 4 waves per 256-thread block.
// All 16 input dwordx4 loads are issued up-front and held live (forces the
// register allocator to keep them in flight -> max memory-level parallelism),
// the two rows' butterfly reduces interleave (6 values/level) to hide DPP
// latency, and gamma/beta are loaded once and applied to both rows.
// Curvature is read with non-temporal loads (pure stream, keep it out of L3
// so the 134 MB embeddings stream stays Infinity-Cache-resident) and the
// output is written with non-temporal stores (no write-allocate pollution).
__global__ __launch_bounds__(256) void fieldnorm_kernel(
    const float* __restrict__ emb,
    const float* __restrict__ curv,
    const float* __restrict__ gamma,
    const float* __restrict__ beta,
    const float* __restrict__ cscale,
    float* __restrict__ out)
{
    const int wave = threadIdx.x >> 6;              // 0..3
    const int lane = threadIdx.x & 63;
    const int wid  = blockIdx.x * 4 + wave;         // global wave id
    const long long base0 = (long long)(wid * 2) * D;
    const long long base1 = base0 + D;

    const f4* __restrict__ xp0 = reinterpret_cast<const f4*>(emb + base0);
    const f4* __restrict__ xp1 = reinterpret_cast<const f4*>(emb + base1);
    const f4* __restrict__ cp0 = reinterpret_cast<const f4*>(curv + base0);
    const f4* __restrict__ cp1 = reinterpret_cast<const f4*>(curv + base1);

    // Issue all 16 loads before any consumption.
    f4 x0[4], x1[4], c0[4], c1[4];
    #pragma unroll
    for (int j = 0; j < 4; ++j) {
        x0[j] = xp0[lane + 64 * j];
        x1[j] = xp1[lane + 64 * j];
    }
    #pragma unroll
    for (int j = 0; j < 4; ++j) {
        c0[j] = __builtin_nontemporal_load(&cp0[lane + 64 * j]);
        c1[j] = __builtin_nontemporal_load(&cp1[lane + 64 * j]);
    }

    float sx0 = 0.f, sq0 = 0.f, sc0 = 0.f;
    float sx1 = 0.f, sq1 = 0.f, sc1 = 0.f;
    #pragma unroll
    for (int j = 0; j < 4; ++j) {
        sx0 += (x0[j].x + x0[j].y) + (x0[j].z + x0[j].w);
        sq0 += (x0[j].x * x0[j].x + x0[j].y * x0[j].y)
             + (x0[j].z * x0[j].z + x0[j].w * x0[j].w);
        sc0 += (c0[j].x * c0[j].x + c0[j].y * c0[j].y)
             + (c0[j].z * c0[j].z + c0[j].w * c0[j].w);
        sx1 += (x1[j].x + x1[j].y) + (x1[j].z + x1[j].w);
        sq1 += (x1[j].x * x1[j].x + x1[j].y * x1[j].y)
             + (x1[j].z * x1[j].z + x1[j].w * x1[j].w);
        sc1 += (c1[j].x * c1[j].x + c1[j].y * c1[j].y)
             + (c1[j].z * c1[j].z + c1[j].w * c1[j].w);
    }

    // Wave-wide butterfly: 6 independent values per level -> good ILP.
    #pragma unroll
    for (int off = 32; off > 0; off >>= 1) {
        sx0 += __shfl_xor(sx0, off, 64);
        sq0 += __shfl_xor(sq0, off, 64);
        sc0 += __shfl_xor(sc0, off, 64);
        sx1 += __shfl_xor(sx1, off, 64);
        sq1 += __shfl_xor(sq1, off, 64);
        sc1 += __shfl_xor(sc1, off, 64);
    }

    const float inv_d = 1.0f / (float)D;
    const float cs    = cscale[0];

    const float mean0 = sx0 * inv_d;
    const float var0  = sq0 * inv_d - mean0 * mean0;
    const float s0    = rsqrtf(var0 + EPS) / (1.0f + cs * sqrtf(sc0 + EPS));

    const float mean1 = sx1 * inv_d;
    const float var1  = sq1 * inv_d - mean1 * mean1;
    const float s1    = rsqrtf(var1 + EPS) / (1.0f + cs * sqrtf(sc1 + EPS));

    const f4* __restrict__ gp = reinterpret_cast<const f4*>(gamma);
    const f4* __restrict__ bp = reinterpret_cast<const f4*>(beta);
    f4* __restrict__ op0 = reinterpret_cast<f4*>(out + base0);
    f4* __restrict__ op1 = reinterpret_cast<f4*>(out + base1);

    #pragma unroll
    for (int j = 0; j < 4; ++j) {
        const int idx = lane + 64 * j;
        const f4 g = gp[idx];       // L2/L1-hot, shared by both rows
        const f4 b = bp[idx];
        f4 o0, o1;
        o0.x = (x0[j].x - mean0) * s0 * g.x + b.x;
        o0.y = (x0[j].y - mean0) * s0 * g.y + b.y;
        o0.z = (x0[j].z - mean0) * s0 * g.z + b.z;
        o0.w = (x0[j].w - mean0) * s0 * g.w + b.w;
        o1.x = (x1[j].x - mean1) * s1 * g.x + b.x;
        o1.y = (x1[j].y - mean1) * s1 * g.y + b.y;
        o1.z = (x1[j].z - mean1) * s1 * g.z + b.z;
        o1.w = (x1[j].w - mean1) * s1 * g.w + b.w;
        __builtin_nontemporal_store(o0, &op0[idx]);
        __builtin_nontemporal_store(o1, &op1[idx]);
    }
}

extern "C" void kernel_launch(void* const* d_in, const int* in_sizes, int n_in,
                              void* d_out, int out_size, void* d_ws, size_t ws_size,
                              hipStream_t stream) {
    const float* emb    = (const float*)d_in[0];
    const float* curv   = (const float*)d_in[1];
    const float* gamma  = (const float*)d_in[2];
    const float* beta   = (const float*)d_in[3];
    const float* cscale = (const float*)d_in[4];
    float* out = (float*)d_out;

    const int rows  = out_size / D;        // B*S = 32768
    const int waves = rows / 2;            // 16384 waves
    fieldnorm_kernel<<<waves / 4, 256, 0, stream>>>(emb, curv, gamma, beta, cscale, out);
}

// Round 5
// 63.537 us; speedup vs baseline: 1.0223x; 1.0223x over previous
//
#include <hip/hip_runtime.h>

#define D 1024
#define EPS 1e-6f

// Native clang vector type: accepted by __builtin_nontemporal_{load,store}.
typedef float f4 __attribute__((ext_vector_type(4)));

// Persistent-wave, 2-deep software pipeline.
// 8192 waves (2048 blocks x 4 waves); each wave owns 4 rows at stride 8192
// (grid sweeps contiguous 32MB slabs). Two alternating register buffers:
// while row k is reduced+stored, row k+1's 8 dwordx4 loads are in flight
// (compiler emits partial vmcnt waits, no dead stall). gamma/beta loaded
// once per wave, held in registers across all 4 rows. Curvature NT-load /
// output NT-store keep the 134MB embeddings stream Infinity-Cache-resident.
__global__ __launch_bounds__(256) void fieldnorm_kernel(
    const float* __restrict__ emb,
    const float* __restrict__ curv,
    const float* __restrict__ gamma,
    const float* __restrict__ beta,
    const float* __restrict__ cscale,
    float* __restrict__ out)
{
    const int wave = threadIdx.x >> 6;              // 0..3
    const int lane = threadIdx.x & 63;
    const int wid  = blockIdx.x * 4 + wave;         // 0..8191
    const int NW   = gridDim.x * 4;                 // 8192 waves

    // gamma/beta: resident for the whole wave (L2-hot loads, once).
    f4 g[4], b[4];
    #pragma unroll
    for (int j = 0; j < 4; ++j) {
        g[j] = reinterpret_cast<const f4*>(gamma)[lane + 64 * j];
        b[j] = reinterpret_cast<const f4*>(beta)[lane + 64 * j];
    }
    const float cs    = cscale[0];
    const float inv_d = 1.0f / (float)D;

    const long long base0 = (long long)(wid + 0 * NW) * D;
    const long long base1 = (long long)(wid + 1 * NW) * D;
    const long long base2 = (long long)(wid + 2 * NW) * D;
    const long long base3 = (long long)(wid + 3 * NW) * D;

    f4 xa[4], ca[4], xb[4], cb[4];

#define LOADROW(X, C, BASE)                                                   \
    do {                                                                      \
        const f4* __restrict__ xp = reinterpret_cast<const f4*>(emb + (BASE));\
        const f4* __restrict__ cp = reinterpret_cast<const f4*>(curv + (BASE));\
        _Pragma("unroll")                                                     \
        for (int j = 0; j < 4; ++j) {                                         \
            X[j] = xp[lane + 64 * j];                                         \
            C[j] = __builtin_nontemporal_load(&cp[lane + 64 * j]);            \
        }                                                                     \
    } while (0)

#define PROCROW(X, C, BASE)                                                   \
    do {                                                                      \
        float sx = 0.f, sq = 0.f, sc = 0.f;                                   \
        _Pragma("unroll")                                                     \
        for (int j = 0; j < 4; ++j) {                                         \
            sx += (X[j].x + X[j].y) + (X[j].z + X[j].w);                      \
            sq += (X[j].x * X[j].x + X[j].y * X[j].y)                         \
                + (X[j].z * X[j].z + X[j].w * X[j].w);                        \
            sc += (C[j].x * C[j].x + C[j].y * C[j].y)                         \
                + (C[j].z * C[j].z + C[j].w * C[j].w);                        \
        }                                                                     \
        _Pragma("unroll")                                                     \
        for (int off = 32; off > 0; off >>= 1) {                              \
            sx += __shfl_xor(sx, off, 64);                                    \
            sq += __shfl_xor(sq, off, 64);                                    \
            sc += __shfl_xor(sc, off, 64);                                    \
        }                                                                     \
        const float mean = sx * inv_d;                                        \
        const float var  = sq * inv_d - mean * mean;                          \
        const float s    = rsqrtf(var + EPS) / (1.0f + cs * sqrtf(sc + EPS));  \
        f4* __restrict__ op = reinterpret_cast<f4*>(out + (BASE));            \
        _Pragma("unroll")                                                     \
        for (int j = 0; j < 4; ++j) {                                         \
            f4 o;                                                             \
            o.x = (X[j].x - mean) * s * g[j].x + b[j].x;                      \
            o.y = (X[j].y - mean) * s * g[j].y + b[j].y;                      \
            o.z = (X[j].z - mean) * s * g[j].z + b[j].z;                      \
            o.w = (X[j].w - mean) * s * g[j].w + b[j].w;                      \
            __builtin_nontemporal_store(o, &op[lane + 64 * j]);               \
        }                                                                     \
    } while (0)

    // 2-deep pipeline, fully unrolled with static buffer names.
    LOADROW(xa, ca, base0);
    LOADROW(xb, cb, base1);
    PROCROW(xa, ca, base0);
    LOADROW(xa, ca, base2);
    PROCROW(xb, cb, base1);
    LOADROW(xb, cb, base3);
    PROCROW(xa, ca, base2);
    PROCROW(xb, cb, base3);

#undef LOADROW
#undef PROCROW
}

extern "C" void kernel_launch(void* const* d_in, const int* in_sizes, int n_in,
                              void* d_out, int out_size, void* d_ws, size_t ws_size,
                              hipStream_t stream) {
    const float* emb    = (const float*)d_in[0];
    const float* curv   = (const float*)d_in[1];
    const float* gamma  = (const float*)d_in[2];
    const float* beta   = (const float*)d_in[3];
    const float* cscale = (const float*)d_in[4];
    float* out = (float*)d_out;

    const int rows   = out_size / D;   // 32768
    const int waves  = rows / 4;       // 8192 (4 rows per wave)
    const int blocks = waves / 4;      // 2048
    fieldnorm_kernel<<<blocks, 256, 0, stream>>>(emb, curv, gamma, beta, cscale, out);
}